// Round 1
// 955.576 us; speedup vs baseline: 1.0071x; 1.0071x over previous
//
#include <hip/hip_runtime.h>
#include <math.h>

#define TT 512
#define BB 4096
#define IN_DIM 12
#define HH 32
#define LL 10
#define CC 4
#define NTH (LL * 64)        // 640 threads = 10 waves, one per layer

typedef _Float16 half8 __attribute__((ext_vector_type(8)));
typedef _Float16 half4 __attribute__((ext_vector_type(4)));
typedef float f32x4 __attribute__((ext_vector_type(4)));

#define LOG2E 1.44269504088896340736f

// f16-unit offsets in the LDS arena (total 31744 f16 = 62 KB static):
//  H_HI: per-layer h hi panels, 4 slots (mod-4 of t) — cross-wave handoff
//  H_LO: per-layer h lo panels, 2 slots — wave-internal (own recurrence only)
//  X_HI: wave-0 x panels, 2 slots — wave-internal
#define H_HI 0
#define H_LO (LL * 4 * 512)             // 20480
#define X_HI (H_LO + LL * 2 * 512)      // 30720
#define LDS16_TOT (X_HI + 2 * 512)      // 31744

#define MFMA_(A, B, C) C = __builtin_amdgcn_mfma_f32_16x16x32_f16(A, B, C, 0, 0, 0)

// Fused 10-layer GRU: temporal pipeline across 10 waves, MFMA cells,
// SELF-TIMED producer-consumer sync (no __syncthreads in the main loop).
//
// Round 0 (this session): counters showed the critical 3-wave SIMDs are
// issue-bound with VALU ~2x MFMA, and the VALU busy is dominated by the
// 48 transcendentals/substep (24 exp2 + 24 rcp) issuing at ~16 cyc each.
// Changes:
//  (a) batched reciprocals: 1 rcp per 4 sigmoid denominators (r/z of a
//      row-pair) + 1 rcp per 2 tanh denominators -> 24 rcp/substep -> 8.
//      Denominator products <= ~2^40 (pre-activations are small), so no
//      overflow; relative error ~2^-21, negligible vs the 2^-7 budget.
//  (b) bias folded into the C operand of the first MFMA of each acc tile
//      (kills the 32 v_mov acc-init; identical accumulation order).
__global__ __launch_bounds__(NTH, 2)
void gru_fused_mfma(const float* __restrict__ x,      // [T][B][12]
                    const float* __restrict__ Wih0,   // [96][12]
                    const float* __restrict__ Whh0,   // [96][32]
                    const float* __restrict__ bih0,   // [96]
                    const float* __restrict__ bhh0,   // [96]
                    const float* __restrict__ Wih,    // [9][96][32]
                    const float* __restrict__ Whh,    // [9][96][32]
                    const float* __restrict__ bih,    // [9][96]
                    const float* __restrict__ bhh,    // [9][96]
                    const int*   __restrict__ lengths,
                    float*       __restrict__ last)   // [B][32]
{
    __shared__ __align__(16) _Float16 lds16[LDS16_TOT];
    __shared__ int flagS[LL];    // producer progress
    __shared__ int rflagS[LL];   // consumer progress (indexed by producer)

    const int tid  = threadIdx.x;
    const int w    = tid >> 6;      // layer
    const int lane = tid & 63;
    const int bi16 = lane & 15;     // batch col within group
    const int quad = lane >> 4;
    const int bg   = blockIdx.x;    // batch group (16 elems)

    // ---- zero the arena (h0 = 0, zero-padding) + init flags ----
    {
        float4 z4 = make_float4(0.f, 0.f, 0.f, 0.f);
        float4* p = (float4*)lds16;
        for (int i = tid; i < LDS16_TOT / 8; i += NTH) p[i] = z4;
    }
    if (lane == 0) { flagS[w] = -1; rflagS[w] = -1; }
    __syncthreads();

    // ---- per-wave weight pointers ----
    const float *Wi, *Wh, *bivec, *bhvec;
    int wistride;
    if (w == 0) { Wi = Wih0; Wh = Whh0; bivec = bih0; bhvec = bhh0; wistride = IN_DIM; }
    else {
        Wi = Wih + (size_t)(w - 1) * 96 * HH;
        Wh = Whh + (size_t)(w - 1) * 96 * HH;
        bivec = bih + (size_t)(w - 1) * 96;
        bhvec = bhh + (size_t)(w - 1) * 96;
        wistride = HH;
    }

    // ---- stationary A-fragments (pre-scaled) ----
    // f0..f7: r/z tiles, pairs (chunk0=Wi, chunk1=Wh); f8,f9: IN (Wi);
    // f10,f11: HN (Wh). Wlo kept only for the 6 h-side (Wh) frags.
    const int frow[12] = {0, 0, 16, 16, 32, 32, 48, 48, 64, 80, 64, 80};
    const int fchk[12] = {0, 1, 0, 1, 0, 1, 0, 1, 0, 0, 1, 1};
    half8 Whi[12], Wlo[6];
#pragma unroll
    for (int f = 0; f < 12; f++) {
        const float sc = (f < 8) ? -LOG2E : 2.0f * LOG2E;
        int row = frow[f] + bi16;
        const float* src; int kin;
        if (fchk[f] == 0) { src = Wi + (size_t)row * wistride; kin = wistride; }
        else              { src = Wh + (size_t)row * HH;       kin = HH; }
        int wloidx = (f < 8) ? (f >> 1) : (f - 6);
#pragma unroll
        for (int kk = 0; kk < 8; kk++) {
            int k = quad * 8 + kk;
            float v = (k < kin) ? src[k] * sc : 0.0f;
            _Float16 h = (_Float16)v;
            Whi[f][kk] = h;
            if (fchk[f] == 1) Wlo[wloidx][kk] = (_Float16)(v - (float)h);
        }
    }

    // ---- biases in registers (pre-scaled, per C-tile f32x4) ----
    f32x4 biasreg[8];
#pragma unroll
    for (int ct = 0; ct < 8; ct++) {
        int g = ct >> 1, jt = ct & 1;
#pragma unroll
        for (int r = 0; r < 4; r++) {
            int j = jt * 16 + quad * 4 + r;
            float v;
            if      (g == 0) v = -(bivec[j]      + bhvec[j])      * LOG2E;
            else if (g == 1) v = -(bivec[32 + j] + bhvec[32 + j]) * LOG2E;
            else if (g == 2) v = bivec[64 + j] * (2.0f * LOG2E);
            else             v = bhvec[64 + j] * (2.0f * LOG2E);
            biasreg[ct][r] = v;
        }
    }

    int capT = -1;   // last-layer capture timestep per lane
    if (w == LL - 1) {
        int len = lengths[bg * 16 + bi16];
        capT = ((len < 1) ? 1 : len) - 1;
    }

    const int laneoff = lane * 8;
    const int inbase  = (w == 0) ? X_HI : (H_HI + (w - 1) * 2048);
    const int inmask  = (w == 0) ? 1 : 3;
    const int ownhi   = H_HI + w * 2048;
    const int ownlo   = H_LO + w * 1024;
    const int wibase  = (quad >> 1) * 128 + bi16 * 8 + (quad & 1) * 4;

    // x staging constants (wave 0, lanes 0-47)
    const int xbb = lane / 3, xkg = lane - xbb * 3;
    const int xq   = (xkg == 2) ? 1 : 0;
    const int xoff = (xkg == 1) ? 4 : 0;
    const int xidx = xq * 128 + xbb * 8 + xoff;
    const bool xlane = (w == 0) && (lane < 48);

    auto stage_x = [&](const float4& xl, int t) {
        half4 h4;
        h4[0] = (_Float16)xl.x; h4[1] = (_Float16)xl.y;
        h4[2] = (_Float16)xl.z; h4[3] = (_Float16)xl.w;
        *(half4*)(lds16 + X_HI + ((t & 1) << 9) + xidx) = h4;
    };

    // stage x[0], x[1]
    if (xlane) {
        float4 x0 = *(const float4*)(x + (size_t)bg * 192 + lane * 4);
        float4 x1 = *(const float4*)(x + (size_t)BB * IN_DIM + (size_t)bg * 192 + lane * 4);
        stage_x(x0, 0);
        stage_x(x1, 1);
    }

    float hprev[8] = {0, 0, 0, 0, 0, 0, 0, 0};
    __syncthreads();   // flags + h0 + x0/x1 visible before self-timed phase

    auto substep = [&](int t) {
        // B-fragments: input (f16 hi only) + own h (hi+lo)
        half8 bxh = *(const half8*)(lds16 + inbase + ((t & inmask) << 9) + laneoff);
        half8 bhh = *(const half8*)(lds16 + ownhi + (((t + 3) & 3) << 9) + laneoff);
        half8 bhl = *(const half8*)(lds16 + ownlo + (((t + 1) & 1) << 9) + laneoff);

        f32x4 acc[8];

        // 24 MFMAs: r/z tiles 4 each; IN 1 each; HN 3 each.
        // First MFMA of each tile takes biasreg as the C operand directly
        // (no acc-init movs; accumulation order identical to before).
#pragma unroll
        for (int ct = 0; ct < 4; ct++) {
            acc[ct] = __builtin_amdgcn_mfma_f32_16x16x32_f16(
                          Whi[ct * 2 + 0], bxh, biasreg[ct], 0, 0, 0);
            MFMA_(Whi[ct * 2 + 1], bhh, acc[ct]);
            MFMA_(Whi[ct * 2 + 1], bhl, acc[ct]);
            MFMA_(Wlo[ct],         bhh, acc[ct]);
        }
#pragma unroll
        for (int jt = 0; jt < 2; jt++) {
            acc[4 + jt] = __builtin_amdgcn_mfma_f32_16x16x32_f16(
                              Whi[8 + jt], bxh, biasreg[4 + jt], 0, 0, 0);
            acc[6 + jt] = __builtin_amdgcn_mfma_f32_16x16x32_f16(
                              Whi[10 + jt], bhh, biasreg[6 + jt], 0, 0, 0);
            MFMA_(Whi[10 + jt], bhl, acc[6 + jt]);
            MFMA_(Wlo[4 + jt],  bhh, acc[6 + jt]);
        }

        // epilogue with BATCHED reciprocals (8 rcp/substep instead of 24):
        // r = 1/(1+exp2(accR)), z likewise — one rcp per 4 denominators
        // (r/z of a row-pair), reconstructed via multiplies;
        // n = 1 - 2/(exp2(IN + r*HN)+1) — one rcp per 2 denominators.
        // Denominator products <= ~2^40: no overflow; err ~2^-21 relative.
#pragma unroll
        for (int jt = 0; jt < 2; jt++) {
            f32x4 R = acc[0 + jt], Z = acc[2 + jt];
            f32x4 IN_ = acc[4 + jt], HN = acc[6 + jt];
            half4 h4, l4;
            float hv[4];
#pragma unroll
            for (int pr = 0; pr < 2; pr++) {        // row pairs (0,1),(2,3)
                const int r0 = pr * 2, r1 = pr * 2 + 1;
                float a0 = 1.0f + __builtin_amdgcn_exp2f(R[r0]);
                float b0 = 1.0f + __builtin_amdgcn_exp2f(Z[r0]);
                float a1 = 1.0f + __builtin_amdgcn_exp2f(R[r1]);
                float b1 = 1.0f + __builtin_amdgcn_exp2f(Z[r1]);
                float p0 = a0 * b0, p1 = a1 * b1;
                float q  = __builtin_amdgcn_rcpf(p0 * p1);
                float q0 = q * p1, q1 = q * p0;       // = 1/p0, 1/p1
                float rv0 = q0 * b0, zv0 = q0 * a0;   // = 1/a0, 1/b0
                float rv1 = q1 * b1, zv1 = q1 * a1;
                float ea0 = __builtin_amdgcn_exp2f(fmaf(rv0, HN[r0], IN_[r0]));
                float ea1 = __builtin_amdgcn_exp2f(fmaf(rv1, HN[r1], IN_[r1]));
                float d0 = ea0 + 1.0f, d1 = ea1 + 1.0f;
                float qn = __builtin_amdgcn_rcpf(d0 * d1);
                float nv0 = fmaf(-2.0f, qn * d1, 1.0f);
                float nv1 = fmaf(-2.0f, qn * d0, 1.0f);
                float h0 = fmaf(zv0, hprev[jt * 4 + r0] - nv0, nv0);
                float h1 = fmaf(zv1, hprev[jt * 4 + r1] - nv1, nv1);
                hprev[jt * 4 + r0] = h0;
                hprev[jt * 4 + r1] = h1;
                _Float16 hh0 = (_Float16)h0, hh1 = (_Float16)h1;
                h4[r0] = hh0; h4[r1] = hh1;
                l4[r0] = (_Float16)(h0 - (float)hh0);
                l4[r1] = (_Float16)(h1 - (float)hh1);
                hv[r0] = h0; hv[r1] = h1;
            }
            int wi = jt * 256 + wibase;
            *(half4*)(lds16 + ownhi + ((t & 3) << 9) + wi) = h4;
            *(half4*)(lds16 + ownlo + ((t & 1) << 9) + wi) = l4;
            if (w == LL - 1 && t == capT) {
                float4 o = make_float4(hv[0], hv[1], hv[2], hv[3]);
                *(float4*)(last + (size_t)(bg * 16 + bi16) * HH + jt * 16 + quad * 4) = o;
            }
        }
    };

    for (int t = 0; t < TT; t += 2) {
        // fwd sync: input panels for t, t+1 published by wave w-1
        if (w > 0) {
            while (__hip_atomic_load(&flagS[w - 1], __ATOMIC_ACQUIRE,
                                     __HIP_MEMORY_SCOPE_WORKGROUP) < t + 1)
                __builtin_amdgcn_s_sleep(1);
        }
        // bwd sync: writing t+1 reuses slot of t-3 — consumer must be done
        if (w < LL - 1) {
            while (__hip_atomic_load(&rflagS[w], __ATOMIC_ACQUIRE,
                                     __HIP_MEMORY_SCOPE_WORKGROUP) < t - 3)
                __builtin_amdgcn_s_sleep(1);
        }

        // wave 0: issue global x loads for t+2, t+3 early
        float4 xa0, xa1;
        bool dl0 = false, dl1 = false;
        if (xlane) {
            if (t + 2 < TT) {
                xa0 = *(const float4*)(x + (size_t)(t + 2) * BB * IN_DIM +
                                       (size_t)bg * 192 + lane * 4);
                dl0 = true;
            }
            if (t + 3 < TT) {
                xa1 = *(const float4*)(x + (size_t)(t + 3) * BB * IN_DIM +
                                       (size_t)bg * 192 + lane * 4);
                dl1 = true;
            }
        }

        substep(t);
        substep(t + 1);

        if (dl0) stage_x(xa0, t + 2);   // slot t&1 already read in substep(t)
        if (dl1) stage_x(xa1, t + 3);

        if (lane == 0) {
            // release: waits for this wave's DS ops (panel writes AND input
            // reads) to drain before publishing
            if (w < LL - 1)
                __hip_atomic_store(&flagS[w], t + 1, __ATOMIC_RELEASE,
                                   __HIP_MEMORY_SCOPE_WORKGROUP);
            if (w > 0)
                __hip_atomic_store(&rflagS[w - 1], t + 1, __ATOMIC_RELEASE,
                                   __HIP_MEMORY_SCOPE_WORKGROUP);
        }
    }
}

__global__ __launch_bounds__(256)
void fc_head(const float* __restrict__ last,
             const float* __restrict__ fcW,   // [C][H]
             const float* __restrict__ fcb,   // [C]
             float* __restrict__ out)         // [B][C]
{
    int b = blockIdx.x * blockDim.x + threadIdx.x;
    if (b >= BB) return;
    float lg[CC];
#pragma unroll
    for (int c = 0; c < CC; c++) lg[c] = fcb[c];
#pragma unroll
    for (int j = 0; j < HH; j++) {
        float h = last[(size_t)b * HH + j];
#pragma unroll
        for (int c = 0; c < CC; c++) lg[c] = fmaf(fcW[c * HH + j], h, lg[c]);
    }
    float m = lg[0];
#pragma unroll
    for (int c = 1; c < CC; c++) m = fmaxf(m, lg[c]);
    float s = 0.0f;
#pragma unroll
    for (int c = 0; c < CC; c++) s += __expf(lg[c] - m);
    float lse = m + logf(s);
#pragma unroll
    for (int c = 0; c < CC; c++) out[(size_t)b * CC + c] = lg[c] - lse;
}

extern "C" void kernel_launch(void* const* d_in, const int* in_sizes, int n_in,
                              void* d_out, int out_size, void* d_ws, size_t ws_size,
                              hipStream_t stream)
{
    const float* x    = (const float*)d_in[0];
    const float* Wih0 = (const float*)d_in[1];
    const float* Whh0 = (const float*)d_in[2];
    const float* bih0 = (const float*)d_in[3];
    const float* bhh0 = (const float*)d_in[4];
    const float* Wih  = (const float*)d_in[5];
    const float* Whh  = (const float*)d_in[6];
    const float* bih  = (const float*)d_in[7];
    const float* bhh  = (const float*)d_in[8];
    const float* fcW  = (const float*)d_in[9];
    const float* fcb  = (const float*)d_in[10];
    const int*   lens = (const int*)d_in[11];
    float* out = (float*)d_out;

    float* last = (float*)d_ws;   // [B][32] = 512 KB

    gru_fused_mfma<<<dim3(BB / 16), dim3(NTH), 0, stream>>>(
        x, Wih0, Whh0, bih0, bhh0, Wih, Whh, bih, bhh, lens, last);

    fc_head<<<dim3(BB / 256), dim3(256), 0, stream>>>(last, fcW, fcb, out);
}